// Round 3
// baseline (322.690 us; speedup 1.0000x reference)
//
#include <hip/hip_runtime.h>
#include <hip/hip_bf16.h>
#include <math.h>

// EdgeDistancesPassing: out[e] = exp(-relu(relu((f[src]-f[dst])@W1 + b1)@W2 + b2)) * f[dst]
// Linearity: (f[src]-f[dst])@W1 = P[src]-P[dst] with P = features@W1 (b1 added per-edge).

#define D 64
#define NPB 64   // nodes per block in projection kernel
#define U 4      // edges per 16-lane group in edge kernel (ILP unroll)

typedef float nfloat4 __attribute__((ext_vector_type(4)));  // native vec for nontemporal builtin

// ---------------- Kernel 1: P = features @ W1 (register-tiled 4x4) ----------------
__global__ __launch_bounds__(256) void node_proj_kernel(
    const float* __restrict__ F, const float* __restrict__ W1,
    float* __restrict__ P, int n_nodes)
{
    __shared__ float4 sW4[D * 16];    // [k][col4], 16 KB
    __shared__ float4 sF4[NPB * 16];  // [node][k4], 16 KB

    const int tid = threadIdx.x;
    const int base = blockIdx.x * NPB;
    const int nrows = min(NPB, n_nodes - base);

    // Stage W1: 1024 float4 / 256 threads (coalesced)
    const float4* W4 = (const float4*)W1;
#pragma unroll
    for (int i = 0; i < 4; ++i) sW4[tid + i * 256] = W4[tid + i * 256];

    // Stage feature rows (coalesced, identity layout copy)
    const float4* Fg = (const float4*)(F + (long)base * D);
    const int totalf4 = nrows * 16;
    for (int i = tid; i < totalf4; i += 256) sF4[i] = Fg[i];
    __syncthreads();

    const int tx = tid & 15;   // col group (cols 4tx..4tx+3)
    const int ty = tid >> 4;   // node group (nodes 4ty..4ty+3)

    float4 acc[4];
#pragma unroll
    for (int i = 0; i < 4; ++i) { acc[i].x = 0.f; acc[i].y = 0.f; acc[i].z = 0.f; acc[i].w = 0.f; }

#pragma unroll
    for (int k4 = 0; k4 < 16; ++k4) {
        float4 wr[4], fr[4];
#pragma unroll
        for (int r = 0; r < 4; ++r) wr[r] = sW4[(k4 * 4 + r) * 16 + tx];  // b128, 2-way/bcast
#pragma unroll
        for (int i = 0; i < 4; ++i) fr[i] = sF4[(ty * 4 + i) * 16 + k4]; // b128, broadcast
#pragma unroll
        for (int i = 0; i < 4; ++i) {
            acc[i].x += fr[i].x * wr[0].x + fr[i].y * wr[1].x + fr[i].z * wr[2].x + fr[i].w * wr[3].x;
            acc[i].y += fr[i].x * wr[0].y + fr[i].y * wr[1].y + fr[i].z * wr[2].y + fr[i].w * wr[3].y;
            acc[i].z += fr[i].x * wr[0].z + fr[i].y * wr[1].z + fr[i].z * wr[2].z + fr[i].w * wr[3].z;
            acc[i].w += fr[i].x * wr[0].w + fr[i].y * wr[1].w + fr[i].z * wr[2].w + fr[i].w * wr[3].w;
        }
    }

#pragma unroll
    for (int i = 0; i < 4; ++i) {
        const int n = ty * 4 + i;
        if (n < nrows) ((float4*)P)[(long)(base + n) * 16 + tx] = acc[i];
    }
}

// ---------------- Kernel 2: per-edge fused epilogue ----------------
// 16 lanes per edge, 4 edges per group unrolled straight-line (12 outstanding gathers).
__global__ __launch_bounds__(256, 4) void edge_kernel(
    const float4* __restrict__ P4, const float4* __restrict__ F4,
    const int* __restrict__ src_idx, const int* __restrict__ dst_idx,
    const float* __restrict__ b1, const float* __restrict__ W2,
    const float* __restrict__ b2v,
    float4* __restrict__ out4, int n_edges, int G)
{
    const int lane16 = threadIdx.x & 15;
    const int g = (blockIdx.x * blockDim.x + threadIdx.x) >> 4;

    const float4 b1f = ((const float4*)b1)[lane16];
    const float4 w2f = ((const float4*)W2)[lane16];
    const float b2s = b2v[0];

    int e[U]; bool ok[U]; long s[U], d[U];
#pragma unroll
    for (int j = 0; j < U; ++j) {
        e[j] = g + j * G;                 // consecutive groups -> consecutive edges (coalesced stores)
        ok[j] = e[j] < n_edges;
        const int ee = ok[j] ? e[j] : 0;  // clamp: safe dummy loads for tail
        s[j] = (long)src_idx[ee];
        d[j] = (long)dst_idx[ee];
    }

    float4 ps[U], pd[U], fd[U];
#pragma unroll
    for (int j = 0; j < U; ++j) {
        ps[j] = P4[s[j] * 16 + lane16];
        pd[j] = P4[d[j] * 16 + lane16];
        fd[j] = F4[d[j] * 16 + lane16];
    }

#pragma unroll
    for (int j = 0; j < U; ++j) {
        const float hx = fmaxf(ps[j].x - pd[j].x + b1f.x, 0.f);
        const float hy = fmaxf(ps[j].y - pd[j].y + b1f.y, 0.f);
        const float hz = fmaxf(ps[j].z - pd[j].z + b1f.z, 0.f);
        const float hw = fmaxf(ps[j].w - pd[j].w + b1f.w, 0.f);

        float dot = hx * w2f.x + hy * w2f.y + hz * w2f.z + hw * w2f.w;
        dot += __shfl_xor(dot, 1);
        dot += __shfl_xor(dot, 2);
        dot += __shfl_xor(dot, 4);
        dot += __shfl_xor(dot, 8);

        const float a = __expf(-fmaxf(dot + b2s, 0.f));

        nfloat4 o;
        o.x = a * fd[j].x; o.y = a * fd[j].y; o.z = a * fd[j].z; o.w = a * fd[j].w;
        if (ok[j]) {
            nfloat4* dst = (nfloat4*)&out4[(long)e[j] * 16 + lane16];
            __builtin_nontemporal_store(o, dst);
        }
    }
}

extern "C" void kernel_launch(void* const* d_in, const int* in_sizes, int n_in,
                              void* d_out, int out_size, void* d_ws, size_t ws_size,
                              hipStream_t stream) {
    const float* features = (const float*)d_in[0];
    const int*   src_idx  = (const int*)d_in[1];
    const int*   dst_idx  = (const int*)d_in[2];
    const float* W1       = (const float*)d_in[3];
    const float* b1       = (const float*)d_in[4];
    const float* W2       = (const float*)d_in[5];
    const float* b2       = (const float*)d_in[6];
    float* out = (float*)d_out;

    const int n_nodes = in_sizes[0] / D;
    const int n_edges = in_sizes[1];

    float* P = (float*)d_ws;  // n_nodes * D floats = 12.8 MB

    const int grid1 = (n_nodes + NPB - 1) / NPB;
    node_proj_kernel<<<grid1, 256, 0, stream>>>(features, W1, P, n_nodes);

    // 16 groups/block, U edges/group
    const int grid2 = (n_edges + 16 * U - 1) / (16 * U);
    const int G = grid2 * 16;  // total groups
    edge_kernel<<<grid2, 256, 0, stream>>>((const float4*)P, (const float4*)features,
                                           src_idx, dst_idx, b1, W2, b2,
                                           (float4*)out, n_edges, G);
}

// Round 4
// 298.933 us; speedup vs baseline: 1.0795x; 1.0795x over previous
//
#include <hip/hip_runtime.h>
#include <hip/hip_bf16.h>
#include <math.h>

// EdgeDistancesPassing: out[e] = exp(-relu(relu((f[src]-f[dst])@W1 + b1)@W2 + b2)) * f[dst]
// Linearity: (f[src]-f[dst])@W1 = P[src]-P[dst] with P = features@W1 (b1 added per-edge).
// R4: gather tables stored bf16-packed: T[node] = [P bf16 x64 | F bf16 x64] = 256 B/row.
//     Edge gather traffic 768 -> 384 B/edge. Math in fp32 after conversion.

#define D 64
#define NPB 64   // nodes per block in projection kernel

typedef float nfloat4 __attribute__((ext_vector_type(4)));  // native vec for nontemporal builtin

// round-to-nearest-even fp32 -> bf16 bits (inputs are finite)
static __device__ __forceinline__ unsigned short f2bf(float f) {
    unsigned u = __float_as_uint(f);
    u += 0x7fffu + ((u >> 16) & 1u);
    return (unsigned short)(u >> 16);
}
static __device__ __forceinline__ float bf2f(unsigned short b) {
    return __uint_as_float(((unsigned)b) << 16);
}

// ---------------- Kernel 1: build T = [bf16(F@W1) | bf16(F)] ----------------
__global__ __launch_bounds__(256) void node_proj_kernel(
    const float* __restrict__ F, const float* __restrict__ W1,
    ushort4* __restrict__ T, int n_nodes)   // T: [node][32] ushort4 (256 B/row)
{
    __shared__ float4 sW4[D * 16];    // [k][col4], 16 KB
    __shared__ float4 sF4[NPB * 16];  // [node][k4], 16 KB

    const int tid = threadIdx.x;
    const int base = blockIdx.x * NPB;
    const int nrows = min(NPB, n_nodes - base);

    // Stage W1 (coalesced)
    const float4* W4 = (const float4*)W1;
#pragma unroll
    for (int i = 0; i < 4; ++i) sW4[tid + i * 256] = W4[tid + i * 256];

    // Stage feature rows (coalesced)
    const float4* Fg = (const float4*)(F + (long)base * D);
    const int totalf4 = nrows * 16;
    for (int i = tid; i < totalf4; i += 256) sF4[i] = Fg[i];
    __syncthreads();

    const int tx = tid & 15;   // col group (cols 4tx..4tx+3)
    const int ty = tid >> 4;   // node group (nodes 4ty..4ty+3)

    float4 acc[4];
#pragma unroll
    for (int i = 0; i < 4; ++i) { acc[i].x = 0.f; acc[i].y = 0.f; acc[i].z = 0.f; acc[i].w = 0.f; }

#pragma unroll
    for (int k4 = 0; k4 < 16; ++k4) {
        float4 wr[4], fr[4];
#pragma unroll
        for (int r = 0; r < 4; ++r) wr[r] = sW4[(k4 * 4 + r) * 16 + tx];
#pragma unroll
        for (int i = 0; i < 4; ++i) fr[i] = sF4[(ty * 4 + i) * 16 + k4];
#pragma unroll
        for (int i = 0; i < 4; ++i) {
            acc[i].x += fr[i].x * wr[0].x + fr[i].y * wr[1].x + fr[i].z * wr[2].x + fr[i].w * wr[3].x;
            acc[i].y += fr[i].x * wr[0].y + fr[i].y * wr[1].y + fr[i].z * wr[2].y + fr[i].w * wr[3].y;
            acc[i].z += fr[i].x * wr[0].z + fr[i].y * wr[1].z + fr[i].z * wr[2].z + fr[i].w * wr[3].z;
            acc[i].w += fr[i].x * wr[0].w + fr[i].y * wr[1].w + fr[i].z * wr[2].w + fr[i].w * wr[3].w;
        }
    }

    // Write P half (bf16): row slot tx covers cols 4tx..4tx+3
#pragma unroll
    for (int i = 0; i < 4; ++i) {
        const int n = ty * 4 + i;
        if (n < nrows) {
            ushort4 pu;
            pu.x = f2bf(acc[i].x); pu.y = f2bf(acc[i].y);
            pu.z = f2bf(acc[i].z); pu.w = f2bf(acc[i].w);
            T[(long)(base + n) * 32 + tx] = pu;
        }
    }

    // Write F half (bf16) from staged sF4: 1024 chunks / 256 threads
#pragma unroll
    for (int c = tid; c < NPB * 16; c += 256) {
        const int n = c >> 4;
        if (n < nrows) {
            const int sub = c & 15;
            const float4 f = sF4[c];
            ushort4 fu;
            fu.x = f2bf(f.x); fu.y = f2bf(f.y); fu.z = f2bf(f.z); fu.w = f2bf(f.w);
            T[(long)(base + n) * 32 + 16 + sub] = fu;
        }
    }
}

// ---------------- Kernel 2: per-edge fused epilogue (16 lanes/edge) ----------------
__global__ __launch_bounds__(256) void edge_kernel(
    const ushort4* __restrict__ T,
    const int* __restrict__ src_idx, const int* __restrict__ dst_idx,
    const float* __restrict__ b1, const float* __restrict__ W2,
    const float* __restrict__ b2v,
    float4* __restrict__ out4, int n_edges)
{
    const int tid = blockIdx.x * blockDim.x + threadIdx.x;
    const int lane16 = threadIdx.x & 15;
    const int e = tid >> 4;
    if (e >= n_edges) return;

    const float4 b1f = ((const float4*)b1)[lane16];
    const float4 w2f = ((const float4*)W2)[lane16];
    const float b2s = b2v[0];

    const long s = (long)src_idx[e];
    const long d = (long)dst_idx[e];

    const ushort4 psu = T[s * 32 + lane16];        // P[src] slice (8 B/lane)
    const ushort4 pdu = T[d * 32 + lane16];        // P[dst] slice
    const ushort4 fdu = T[d * 32 + 16 + lane16];   // F[dst] slice (same row as pdu)

    const float hx = fmaxf(bf2f(psu.x) - bf2f(pdu.x) + b1f.x, 0.f);
    const float hy = fmaxf(bf2f(psu.y) - bf2f(pdu.y) + b1f.y, 0.f);
    const float hz = fmaxf(bf2f(psu.z) - bf2f(pdu.z) + b1f.z, 0.f);
    const float hw = fmaxf(bf2f(psu.w) - bf2f(pdu.w) + b1f.w, 0.f);

    float dot = hx * w2f.x + hy * w2f.y + hz * w2f.z + hw * w2f.w;
    dot += __shfl_xor(dot, 1);
    dot += __shfl_xor(dot, 2);
    dot += __shfl_xor(dot, 4);
    dot += __shfl_xor(dot, 8);

    const float a = __expf(-fmaxf(dot + b2s, 0.f));

    nfloat4 o;
    o.x = a * bf2f(fdu.x); o.y = a * bf2f(fdu.y);
    o.z = a * bf2f(fdu.z); o.w = a * bf2f(fdu.w);
    nfloat4* dst = (nfloat4*)&out4[(long)e * 16 + lane16];
    __builtin_nontemporal_store(o, dst);
}

extern "C" void kernel_launch(void* const* d_in, const int* in_sizes, int n_in,
                              void* d_out, int out_size, void* d_ws, size_t ws_size,
                              hipStream_t stream) {
    const float* features = (const float*)d_in[0];
    const int*   src_idx  = (const int*)d_in[1];
    const int*   dst_idx  = (const int*)d_in[2];
    const float* W1       = (const float*)d_in[3];
    const float* b1       = (const float*)d_in[4];
    const float* W2       = (const float*)d_in[5];
    const float* b2       = (const float*)d_in[6];
    float* out = (float*)d_out;

    const int n_nodes = in_sizes[0] / D;
    const int n_edges = in_sizes[1];

    ushort4* T = (ushort4*)d_ws;  // n_nodes * 256 B = 12.8 MB

    const int grid1 = (n_nodes + NPB - 1) / NPB;
    node_proj_kernel<<<grid1, 256, 0, stream>>>(features, W1, T, n_nodes);

    const int groups_per_block = 256 / 16;  // 16 edges per block
    const int grid2 = (n_edges + groups_per_block - 1) / groups_per_block;
    edge_kernel<<<grid2, 256, 0, stream>>>(T, src_idx, dst_idx,
                                           b1, W2, b2, (float4*)out, n_edges);
}